// Round 13
// baseline (209.088 us; speedup 1.0000x reference)
//
#include <hip/hip_runtime.h>
#include <hip/hip_fp16.h>
#include <math.h>

#define N_NODES 50000
#define F_DIM   128
#define E_EDGES 800000
#define NPB     32      // nodes per gemm block -> 1563 blocks (last block 16 rows)
#define NBLK    1563
#define CAP     64      // bucket capacity per node
#define APAD_H  136     // padded row stride in halves (272 B)
#define NMASKW  400000  // 12.8M elements / 32 bits
#define FILL_BLOCKS (E_EDGES / 256)            // 3125
#define PACK_BLOCKS ((N_NODES * F_DIM) / 1024) // 6250
#define WPACK_BLOCKS 64                        // 2*128*64 half2 words / 256

typedef _Float16 h2v __attribute__((ext_vector_type(2)));

// fdot2: 2-way fp16 dot with f32 accumulate (falls back to cvt+fma if unavailable)
__device__ __forceinline__ float fd2(float a, float b, float c) {
#if __has_builtin(__builtin_amdgcn_fdot2)
  return __builtin_amdgcn_fdot2(__builtin_bit_cast(h2v, a),
                                __builtin_bit_cast(h2v, b), c, false);
#else
  float2 fa = __half22float2(__builtin_bit_cast(__half2, a));
  float2 fb = __half22float2(__builtin_bit_cast(__half2, b));
  return fmaf(fa.x, fb.x, fmaf(fa.y, fb.y, c));
#endif
}

// ---------------- JAX threefry (partitionable path, o0^o1) — verified r2 ----------------
__device__ __forceinline__ unsigned rotl32(unsigned x, int d) {
  return (x << d) | (x >> (32 - d));
}

__device__ __forceinline__ void tf2x32(unsigned k0, unsigned k1,
                                       unsigned c0, unsigned c1,
                                       unsigned &o0, unsigned &o1) {
  unsigned ks2 = k0 ^ k1 ^ 0x1BD11BDAu;
  unsigned x0 = c0 + k0, x1 = c1 + k1;
#define TF_R(a) { x0 += x1; x1 = rotl32(x1, a); x1 ^= x0; }
  TF_R(13) TF_R(15) TF_R(26) TF_R(6)   x0 += k1;  x1 += ks2 + 1u;
  TF_R(17) TF_R(29) TF_R(16) TF_R(24)  x0 += ks2; x1 += k0 + 2u;
  TF_R(13) TF_R(15) TF_R(26) TF_R(6)   x0 += k0;  x1 += k1 + 3u;
  TF_R(17) TF_R(29) TF_R(16) TF_R(24)  x0 += k1;  x1 += ks2 + 4u;
  TF_R(13) TF_R(15) TF_R(26) TF_R(6)   x0 += ks2; x1 += k0 + 5u;
#undef TF_R
  o0 = x0; o1 = x1;
}

__device__ __forceinline__ bool keep_elem(unsigned j) {
  unsigned o0, o1;
  tf2x32(0u, 42u, 0u, j, o0, o1);
  unsigned bits = o0 ^ o1;
  float uf = __uint_as_float((bits >> 9) | 0x3f800000u) - 1.0f;
  return uf < 0.7f;
}

// --- prep: bucket+mask | fp16 pack of x | fp16 k-pair pack of W (one overlapped grid) ---
__global__ __launch_bounds__(256) void prep(const float* __restrict__ x,
                                            __half* __restrict__ xh,
                                            const int* __restrict__ src,
                                            const int* __restrict__ dst,
                                            const float* __restrict__ Wself,
                                            const float* __restrict__ Wneigh,
                                            float* __restrict__ Wp,
                                            int* __restrict__ cursor,
                                            int* __restrict__ bucket,
                                            unsigned* __restrict__ mask) {
  int b = blockIdx.x;
  if (b < FILL_BLOCKS) {
    int e = b * 256 + threadIdx.x;
    int d = dst[e];
    int pos = atomicAdd(&cursor[d], 1);
    if (pos < CAP) bucket[d * CAP + pos] = src[e];
    if (e < NMASKW) {                       // threefry hides under atomic latency
      unsigned base = (unsigned)e * 32u;
      unsigned w = 0;
#pragma unroll 4
      for (int bb = 0; bb < 32; ++bb) w |= (keep_elem(base + bb) ? 1u : 0u) << bb;
      mask[e] = w;
    }
  } else if (b < FILL_BLOCKS + PACK_BLOCKS) {
    int i = (b - FILL_BLOCKS) * 256 + threadIdx.x;   // one float4 -> 8B half4
    float4 v = ((const float4*)x)[i];
    __half2 h01 = __floats2half2_rn(v.x, v.y);
    __half2 h23 = __floats2half2_rn(v.z, v.w);
    float2 o;
    o.x = __uint_as_float(*(const unsigned*)&h01);
    o.y = __uint_as_float(*(const unsigned*)&h23);
    ((float2*)xh)[i] = o;
  } else {
    // W pack: Wp[h][c][k2] = half2(W[2k2][c], W[2k2+1][c])
    int idx = (b - FILL_BLOCKS - PACK_BLOCKS) * 256 + threadIdx.x;  // [0, 16384)
    int h = idx >> 13, rem = idx & 8191;
    int k2 = rem >> 7, c = rem & 127;
    const float* Ws = h ? Wneigh : Wself;
    __half2 hh = __floats2half2_rn(Ws[(k2 * 2) * 128 + c], Ws[(k2 * 2 + 1) * 128 + c]);
    Wp[h * 8192 + c * 64 + k2] = __builtin_bit_cast(float, hh);
  }
}

// ---- gather: one 64-lane wave per node; zero LDS; full occupancy; 8 loads in flight ----
// Writes the fp16 mean row (256B) OVER the node's consumed bucket row (same footprint).
__global__ __launch_bounds__(256) void gather_kernel(const __half* __restrict__ xh,
                                                     const int* __restrict__ cursor,
                                                     const int* bucket,
                                                     __half* seg) {
  const int w = threadIdx.x >> 6, li = threadIdx.x & 63;
  const int n = blockIdx.x * 4 + w;          // 12500 * 4 = 50000 exactly
  int deg = cursor[n]; deg = deg < CAP ? deg : CAP;
  float sx = 0.f, sy = 0.f;
  const unsigned* xr = (const unsigned*)xh;  // dword = half2; row stride 64
  const int* ep = bucket + (size_t)n * CAP;  // wave-uniform -> scalar loads
  for (int j0 = 0; j0 < deg; j0 += 8) {
    int idx[8];
#pragma unroll
    for (int k = 0; k < 8; ++k) {
      int j = j0 + k;
      idx[k] = ep[j < deg ? j : deg - 1];    // clamped -> always a valid slot
    }
    unsigned u[8];
#pragma unroll
    for (int k = 0; k < 8; ++k)
      u[k] = xr[(size_t)idx[k] * 64 + li];   // 8 independent coalesced dwords
#pragma unroll
    for (int k = 0; k < 8; ++k)
      if (j0 + k < deg) {
        float2 f = __half22float2(__builtin_bit_cast(__half2, u[k]));
        sx += f.x; sy += f.y;
      }
  }
  float iv = 1.0f / (float)(deg > 1 ? deg : 1);
  __half2 r = __floats2half2_rn(sx * iv, sy * iv);
  ((unsigned*)seg)[(size_t)n * 64 + li] = __builtin_bit_cast(unsigned, r);
}

// ---- gemm: stage xh/seg rows -> dual fp16-dot2 GEMM -> mask epilogue (r12 verbatim) ----
__global__ __launch_bounds__(256) void gemm_kernel(
    const __half* __restrict__ xh, const __half* __restrict__ seg,
    const float* __restrict__ Wp, const float* __restrict__ bias,
    const unsigned* __restrict__ mask, float* __restrict__ out) {
  __shared__ __align__(16) __half Ah[2][NPB][APAD_H];   // 17.4 KB
  __shared__ float rowss[2][NPB];

  const int t = threadIdx.x;
  const int row0 = blockIdx.x * NPB;

  // ---- stage self + mean rows (512 x 16B granules each array, coalesced) ----
#pragma unroll
  for (int k = 0; k < 2; ++k) {
    int q = k * 256 + t;
    int row = q >> 4, f8 = q & 15;
    int grow = row0 + row;
    if (grow > N_NODES - 1) grow = N_NODES - 1;
    *(float4*)&Ah[0][row][f8 * 8] = ((const float4*)xh)[(size_t)grow * 16 + f8];
    *(float4*)&Ah[1][row][f8 * 8] = ((const float4*)seg)[(size_t)grow * 16 + f8];
  }
  __syncthreads();

  // ---- GEMM phase: fp16 dot2, f32 accumulate ----
  const int h = t >> 7, rg = (t >> 4) & 7, cg = t & 15;
  const float4* Ab4 = (const float4*)&Ah[h][0][0];    // row stride 17 float4
  const float4* Wp4 = (const float4*)(Wp + h * 8192); // [c][16 float4 of k-pairs]

  float acc[4][8];
#pragma unroll
  for (int i = 0; i < 4; ++i)
#pragma unroll
    for (int c = 0; c < 8; ++c) acc[i][c] = 0.0f;

  for (int kc = 0; kc < 16; ++kc) {          // 8 k-values (4 half2) per chunk
    float4 wv[8];
#pragma unroll
    for (int c = 0; c < 8; ++c)
      wv[c] = Wp4[(cg * 8 + c) * 16 + kc];
#pragma unroll
    for (int i = 0; i < 4; ++i) {
      float4 av = Ab4[(rg * 4 + i) * 17 + kc];
#pragma unroll
      for (int c = 0; c < 8; ++c) {
        float s = acc[i][c];
        s = fd2(av.x, wv[c].x, s);
        s = fd2(av.y, wv[c].y, s);
        s = fd2(av.z, wv[c].z, s);
        s = fd2(av.w, wv[c].w, s);
        acc[i][c] = s;
      }
    }
  }

  // ---- epilogue: +bias, ELU, dropout (precomputed mask), l2norm, store ----
  float4 b0 = ((const float4*)bias)[h * 32 + cg * 2];
  float4 b1 = ((const float4*)bias)[h * 32 + cg * 2 + 1];
  float bb[8] = {b0.x, b0.y, b0.z, b0.w, b1.x, b1.y, b1.z, b1.w};

  float ss[4];
#pragma unroll
  for (int i = 0; i < 4; ++i) {
    unsigned n = row0 + rg * 4 + i;
    unsigned mw = (n < N_NODES) ? mask[n * 8u + (unsigned)h * 4u + (cg >> 2)] : 0u;
    unsigned sh = (cg & 3) * 8;
    ss[i] = 0.0f;
#pragma unroll
    for (int c = 0; c < 8; ++c) {
      float val = acc[i][c] + bb[c];
      val = (val > 0.0f) ? val : expm1f(val);
      val = ((mw >> (sh + c)) & 1u) ? val * (1.0f / 0.7f) : 0.0f;
      acc[i][c] = val;
      ss[i] = fmaf(val, val, ss[i]);
    }
  }
#pragma unroll
  for (int d = 1; d < 16; d <<= 1)
#pragma unroll
    for (int i = 0; i < 4; ++i) ss[i] += __shfl_xor(ss[i], d, 16);
  if (cg == 0) {
#pragma unroll
    for (int i = 0; i < 4; ++i) rowss[h][rg * 4 + i] = ss[i];
  }
  __syncthreads();

#pragma unroll
  for (int i = 0; i < 4; ++i) {
    int lrow = rg * 4 + i;
    size_t n = (size_t)(row0 + lrow);
    if (n < N_NODES) {
      float scale = rsqrtf(fmaxf(rowss[0][lrow] + rowss[1][lrow], 1e-12f));
      float* op = out + n * 256 + h * 128 + cg * 8;
      float4 o0, o1;
      o0.x = acc[i][0] * scale; o0.y = acc[i][1] * scale;
      o0.z = acc[i][2] * scale; o0.w = acc[i][3] * scale;
      o1.x = acc[i][4] * scale; o1.y = acc[i][5] * scale;
      o1.z = acc[i][6] * scale; o1.w = acc[i][7] * scale;
      *(float4*)op = o0;
      *(float4*)(op + 4) = o1;
    }
  }
}

extern "C" void kernel_launch(void* const* d_in, const int* in_sizes, int n_in,
                              void* d_out, int out_size, void* d_ws, size_t ws_size,
                              hipStream_t stream) {
  const float* x      = (const float*)d_in[0];
  const float* Wself  = (const float*)d_in[1];
  const float* Wneigh = (const float*)d_in[2];
  const float* bias   = (const float*)d_in[3];
  const int*   src    = (const int*)d_in[4];   // jnp.int64 degrades to int32 (x64 off)
  const int*   dst    = (const int*)d_in[5];
  float* out = (float*)d_out;

  char* p = (char*)d_ws;
  int*      cursor = (int*)p;                    // 200,000 B (pad 200,704)
  int*      bucket = (int*)(p + 200704);         // 12,800,000 B  (gather overwrites
  __half*   seg    = (__half*)(p + 200704);      //   consumed rows with fp16 means)
  __half*   xh     = (__half*)(p + 13001728);    // 12,800,000 B
  unsigned* mask   = (unsigned*)(p + 25801728);  // 1,600,000 B
  float*    Wp     = (float*)(p + 27401728);     // 65,536 B (end ~27.5 MB)

  hipMemsetAsync(cursor, 0, 200000, stream);
  prep<<<FILL_BLOCKS + PACK_BLOCKS + WPACK_BLOCKS, 256, 0, stream>>>(
      x, xh, src, dst, Wself, Wneigh, Wp, cursor, bucket, mask);
  gather_kernel<<<N_NODES / 4, 256, 0, stream>>>(xh, cursor, bucket, seg);
  gemm_kernel  <<<NBLK, 256, 0, stream>>>(xh, seg, Wp, bias, mask, out);
}

// Round 14
// 151.558 us; speedup vs baseline: 1.3796x; 1.3796x over previous
//
#include <hip/hip_runtime.h>
#include <hip/hip_fp16.h>
#include <math.h>

#define N_NODES 50000
#define F_DIM   128
#define E_EDGES 800000
#define NPB     32      // nodes per gemm block -> 1563 blocks (last block 16 rows)
#define NBLK    1563
#define CAP     64      // bucket capacity per node
#define APAD_H  136     // padded row stride in halves (272 B)
#define NMASKW  400000  // 12.8M elements / 32 bits
#define FILL_BLOCKS (E_EDGES / 256)            // 3125
#define PACK_BLOCKS ((N_NODES * F_DIM) / 1024) // 6250
#define WPACK_BLOCKS 64                        // 2*128*64 half2 words / 256

typedef _Float16 h2v __attribute__((ext_vector_type(2)));

// fdot2: 2-way fp16 dot with f32 accumulate (falls back to cvt+fma if unavailable)
__device__ __forceinline__ float fd2(float a, float b, float c) {
#if __has_builtin(__builtin_amdgcn_fdot2)
  return __builtin_amdgcn_fdot2(__builtin_bit_cast(h2v, a),
                                __builtin_bit_cast(h2v, b), c, false);
#else
  float2 fa = __half22float2(__builtin_bit_cast(__half2, a));
  float2 fb = __half22float2(__builtin_bit_cast(__half2, b));
  return fmaf(fa.x, fb.x, fmaf(fa.y, fb.y, c));
#endif
}

// ---------------- JAX threefry (partitionable path, o0^o1) — verified r2 ----------------
__device__ __forceinline__ unsigned rotl32(unsigned x, int d) {
  return (x << d) | (x >> (32 - d));
}

__device__ __forceinline__ void tf2x32(unsigned k0, unsigned k1,
                                       unsigned c0, unsigned c1,
                                       unsigned &o0, unsigned &o1) {
  unsigned ks2 = k0 ^ k1 ^ 0x1BD11BDAu;
  unsigned x0 = c0 + k0, x1 = c1 + k1;
#define TF_R(a) { x0 += x1; x1 = rotl32(x1, a); x1 ^= x0; }
  TF_R(13) TF_R(15) TF_R(26) TF_R(6)   x0 += k1;  x1 += ks2 + 1u;
  TF_R(17) TF_R(29) TF_R(16) TF_R(24)  x0 += ks2; x1 += k0 + 2u;
  TF_R(13) TF_R(15) TF_R(26) TF_R(6)   x0 += k0;  x1 += k1 + 3u;
  TF_R(17) TF_R(29) TF_R(16) TF_R(24)  x0 += k1;  x1 += ks2 + 4u;
  TF_R(13) TF_R(15) TF_R(26) TF_R(6)   x0 += ks2; x1 += k0 + 5u;
#undef TF_R
  o0 = x0; o1 = x1;
}

__device__ __forceinline__ bool keep_elem(unsigned j) {
  unsigned o0, o1;
  tf2x32(0u, 42u, 0u, j, o0, o1);
  unsigned bits = o0 ^ o1;
  float uf = __uint_as_float((bits >> 9) | 0x3f800000u) - 1.0f;
  return uf < 0.7f;
}

// --- prep: bucket+mask | fp16 pack of x | fp16 transposed pack of W (one grid) ---
__global__ __launch_bounds__(256) void prep(const float* __restrict__ x,
                                            __half* __restrict__ xh,
                                            const int* __restrict__ src,
                                            const int* __restrict__ dst,
                                            const float* __restrict__ Wself,
                                            const float* __restrict__ Wneigh,
                                            float* __restrict__ Wp,
                                            int* __restrict__ cursor,
                                            int* __restrict__ bucket,
                                            unsigned* __restrict__ mask) {
  int b = blockIdx.x;
  if (b < FILL_BLOCKS) {
    int e = b * 256 + threadIdx.x;
    int d = dst[e];
    int pos = atomicAdd(&cursor[d], 1);
    if (pos < CAP) bucket[d * CAP + pos] = src[e];
    if (e < NMASKW) {                       // threefry hides under atomic latency
      unsigned base = (unsigned)e * 32u;
      unsigned w = 0;
#pragma unroll 4
      for (int bb = 0; bb < 32; ++bb) w |= (keep_elem(base + bb) ? 1u : 0u) << bb;
      mask[e] = w;
    }
  } else if (b < FILL_BLOCKS + PACK_BLOCKS) {
    int i = (b - FILL_BLOCKS) * 256 + threadIdx.x;   // one float4 -> 8B half4
    float4 v = ((const float4*)x)[i];
    __half2 h01 = __floats2half2_rn(v.x, v.y);
    __half2 h23 = __floats2half2_rn(v.z, v.w);
    float2 o;
    o.x = __uint_as_float(*(const unsigned*)&h01);
    o.y = __uint_as_float(*(const unsigned*)&h23);
    ((float2*)xh)[i] = o;
  } else {
    // W pack, coalesced-read layout: dword (h,c,k2) -> float4 slot [kc][cc][cg], lane part k2&3
    //   kc = k2>>2 (8-k chunk), cc = c&7 (col within lane's 8), cg = c>>3 (lane)
    int idx = (b - FILL_BLOCKS - PACK_BLOCKS) * 256 + threadIdx.x;  // [0, 16384)
    int h = idx >> 13, rem = idx & 8191;
    int k2 = rem >> 7, c = rem & 127;
    const float* Ws = h ? Wneigh : Wself;
    __half2 hh = __floats2half2_rn(Ws[(k2 * 2) * 128 + c], Ws[(k2 * 2 + 1) * 128 + c]);
    int kc = k2 >> 2, cc = c & 7, cg = c >> 3;
    int nd = (((kc * 8 + cc) * 16 + cg) << 2) | (k2 & 3);
    Wp[h * 8192 + nd] = __builtin_bit_cast(float, hh);
  }
}

// ---- gather: one 64-lane wave per node; zero LDS; full occupancy; 8 loads in flight ----
// Writes the fp16 mean row (256B) OVER the node's consumed bucket row (same footprint).
__global__ __launch_bounds__(256) void gather_kernel(const __half* __restrict__ xh,
                                                     const int* __restrict__ cursor,
                                                     const int* bucket,
                                                     __half* seg) {
  const int w = threadIdx.x >> 6, li = threadIdx.x & 63;
  const int n = blockIdx.x * 4 + w;          // 12500 * 4 = 50000 exactly
  int deg = cursor[n]; deg = deg < CAP ? deg : CAP;
  float sx = 0.f, sy = 0.f;
  const unsigned* xr = (const unsigned*)xh;  // dword = half2; row stride 64
  const int* ep = bucket + (size_t)n * CAP;  // wave-uniform -> scalar loads
  for (int j0 = 0; j0 < deg; j0 += 8) {
    int idx[8];
#pragma unroll
    for (int k = 0; k < 8; ++k) {
      int j = j0 + k;
      idx[k] = ep[j < deg ? j : deg - 1];    // clamped -> always a valid slot
    }
    unsigned u[8];
#pragma unroll
    for (int k = 0; k < 8; ++k)
      u[k] = xr[(size_t)idx[k] * 64 + li];   // 8 independent coalesced dwords
#pragma unroll
    for (int k = 0; k < 8; ++k)
      if (j0 + k < deg) {
        float2 f = __half22float2(__builtin_bit_cast(__half2, u[k]));
        sx += f.x; sy += f.y;
      }
  }
  float iv = 1.0f / (float)(deg > 1 ? deg : 1);
  __half2 r = __floats2half2_rn(sx * iv, sy * iv);
  ((unsigned*)seg)[(size_t)n * 64 + li] = __builtin_bit_cast(unsigned, r);
}

// ---- gemm: stage xh/seg rows -> dual fp16-dot2 GEMM -> mask epilogue ----
__global__ __launch_bounds__(256) void gemm_kernel(
    const __half* __restrict__ xh, const __half* __restrict__ seg,
    const float* __restrict__ Wp, const float* __restrict__ bias,
    const unsigned* __restrict__ mask, float* __restrict__ out) {
  __shared__ __align__(16) __half Ah[2][NPB][APAD_H];   // 17.4 KB
  __shared__ float rowss[2][NPB];

  const int t = threadIdx.x;
  const int row0 = blockIdx.x * NPB;

  // ---- stage self + mean rows (512 x 16B granules each array, coalesced) ----
#pragma unroll
  for (int k = 0; k < 2; ++k) {
    int q = k * 256 + t;
    int row = q >> 4, f8 = q & 15;
    int grow = row0 + row;
    if (grow > N_NODES - 1) grow = N_NODES - 1;
    *(float4*)&Ah[0][row][f8 * 8] = ((const float4*)xh)[(size_t)grow * 16 + f8];
    *(float4*)&Ah[1][row][f8 * 8] = ((const float4*)seg)[(size_t)grow * 16 + f8];
  }
  __syncthreads();

  // ---- GEMM phase: fp16 dot2, f32 accumulate; W reads now coalesced ----
  const int h = t >> 7, rg = (t >> 4) & 7, cg = t & 15;
  const float4* Ab4 = (const float4*)&Ah[h][0][0];    // row stride 17 float4
  const float4* Wp4 = (const float4*)(Wp + h * 8192); // [kc][c][cg] float4s

  float acc[4][8];
#pragma unroll
  for (int i = 0; i < 4; ++i)
#pragma unroll
    for (int c = 0; c < 8; ++c) acc[i][c] = 0.0f;

  for (int kc = 0; kc < 16; ++kc) {          // 8 k-values (4 half2) per chunk
    float4 wv[8];
#pragma unroll
    for (int c = 0; c < 8; ++c)
      wv[c] = Wp4[(kc * 8 + c) * 16 + cg];   // lanes cg: 256B contiguous
#pragma unroll
    for (int i = 0; i < 4; ++i) {
      float4 av = Ab4[(rg * 4 + i) * 17 + kc];
#pragma unroll
      for (int c = 0; c < 8; ++c) {
        float s = acc[i][c];
        s = fd2(av.x, wv[c].x, s);
        s = fd2(av.y, wv[c].y, s);
        s = fd2(av.z, wv[c].z, s);
        s = fd2(av.w, wv[c].w, s);
        acc[i][c] = s;
      }
    }
  }

  // ---- epilogue: +bias, ELU, dropout (precomputed mask), l2norm, store ----
  float4 b0 = ((const float4*)bias)[h * 32 + cg * 2];
  float4 b1 = ((const float4*)bias)[h * 32 + cg * 2 + 1];
  float bb[8] = {b0.x, b0.y, b0.z, b0.w, b1.x, b1.y, b1.z, b1.w};

  float ss[4];
#pragma unroll
  for (int i = 0; i < 4; ++i) {
    unsigned n = row0 + rg * 4 + i;
    unsigned mw = (n < N_NODES) ? mask[n * 8u + (unsigned)h * 4u + (cg >> 2)] : 0u;
    unsigned sh = (cg & 3) * 8;
    ss[i] = 0.0f;
#pragma unroll
    for (int c = 0; c < 8; ++c) {
      float val = acc[i][c] + bb[c];
      val = (val > 0.0f) ? val : expm1f(val);
      val = ((mw >> (sh + c)) & 1u) ? val * (1.0f / 0.7f) : 0.0f;
      acc[i][c] = val;
      ss[i] = fmaf(val, val, ss[i]);
    }
  }
#pragma unroll
  for (int d = 1; d < 16; d <<= 1)
#pragma unroll
    for (int i = 0; i < 4; ++i) ss[i] += __shfl_xor(ss[i], d, 16);
  if (cg == 0) {
#pragma unroll
    for (int i = 0; i < 4; ++i) rowss[h][rg * 4 + i] = ss[i];
  }
  __syncthreads();

#pragma unroll
  for (int i = 0; i < 4; ++i) {
    int lrow = rg * 4 + i;
    size_t n = (size_t)(row0 + lrow);
    if (n < N_NODES) {
      float scale = rsqrtf(fmaxf(rowss[0][lrow] + rowss[1][lrow], 1e-12f));
      float* op = out + n * 256 + h * 128 + cg * 8;
      float4 o0, o1;
      o0.x = acc[i][0] * scale; o0.y = acc[i][1] * scale;
      o0.z = acc[i][2] * scale; o0.w = acc[i][3] * scale;
      o1.x = acc[i][4] * scale; o1.y = acc[i][5] * scale;
      o1.z = acc[i][6] * scale; o1.w = acc[i][7] * scale;
      *(float4*)op = o0;
      *(float4*)(op + 4) = o1;
    }
  }
}

extern "C" void kernel_launch(void* const* d_in, const int* in_sizes, int n_in,
                              void* d_out, int out_size, void* d_ws, size_t ws_size,
                              hipStream_t stream) {
  const float* x      = (const float*)d_in[0];
  const float* Wself  = (const float*)d_in[1];
  const float* Wneigh = (const float*)d_in[2];
  const float* bias   = (const float*)d_in[3];
  const int*   src    = (const int*)d_in[4];   // jnp.int64 degrades to int32 (x64 off)
  const int*   dst    = (const int*)d_in[5];
  float* out = (float*)d_out;

  char* p = (char*)d_ws;
  int*      cursor = (int*)p;                    // 200,000 B (pad 200,704)
  int*      bucket = (int*)(p + 200704);         // 12,800,000 B  (gather overwrites
  __half*   seg    = (__half*)(p + 200704);      //   consumed rows with fp16 means)
  __half*   xh     = (__half*)(p + 13001728);    // 12,800,000 B
  unsigned* mask   = (unsigned*)(p + 25801728);  // 1,600,000 B
  float*    Wp     = (float*)(p + 27401728);     // 65,536 B (end ~27.5 MB)

  hipMemsetAsync(cursor, 0, 200000, stream);
  prep<<<FILL_BLOCKS + PACK_BLOCKS + WPACK_BLOCKS, 256, 0, stream>>>(
      x, xh, src, dst, Wself, Wneigh, Wp, cursor, bucket, mask);
  gather_kernel<<<N_NODES / 4, 256, 0, stream>>>(xh, cursor, bucket, seg);
  gemm_kernel  <<<NBLK, 256, 0, stream>>>(xh, seg, Wp, bias, mask, out);
}